// Round 13
// baseline (84.737 us; speedup 1.0000x reference)
//
#include <hip/hip_runtime.h>
#include <math.h>

#define HH   1024
#define WW   1024
#define NIMG 32
#define NBLK (NIMG * (WW / 32))     // 1024 blocks: (image, 32-col strip)
#define NT   512
#define BIGD (1<<20)
#define L2E  1.44269504088896340736f

#if __has_builtin(__builtin_amdgcn_exp2f)
#define EXP2F(x) __builtin_amdgcn_exp2f(x)
#else
#define EXP2F(x) exp2f(x)
#endif
#if __has_builtin(__builtin_amdgcn_logf)
#define LOG2F(x) __builtin_amdgcn_logf(x)
#else
#define LOG2F(x) log2f(x)
#endif

// d_ws layout: [0,8192) double bceP[1024]; [8192,12288) u32 totP[1024];
//              [12288,16384) u32 cntP[1024]; [16384] u32 ticket (memset to 0
//              on the stream before every launch -> last arriver draws 1023)

__global__ __launch_bounds__(NT, 8) void dtl_main(const float* __restrict__ pred,
                                                  const float* __restrict__ tgt,
                                                  double* __restrict__ bceP,
                                                  unsigned* __restrict__ totP,
                                                  unsigned* __restrict__ cntP,
                                                  unsigned* __restrict__ ticket,
                                                  float* __restrict__ out) {
    // nibw[row>>6][ quad*8 + (row&7) ] : byte s = nibble-pair for row
    // (row>>6)*64 + s*8 + (row&7), cols quad*4..+3 (T bits0-3, P bits4-7)
    __shared__ unsigned long long nibw[16][64];      // 8 KiB
    __shared__ int st_first[16][32];
    __shared__ int st_last[16][32];
    __shared__ float    rfw[8];
    __shared__ unsigned rtw[8], rcw[8];
    __shared__ int lastFlag;
    __shared__ double             fr8[8];
    __shared__ unsigned long long ft8[8];
    __shared__ unsigned           fc8[8];

    const int tid   = threadIdx.x;
    const int lane  = tid & 63;
    const int wv    = tid >> 6;                      // 0..7
    const int bid   = blockIdx.x;
    const int n     = bid >> 5;                      // image
    const int strip = bid & 31;                      // col base = strip*32

    // ---------------- Phase A: pipelined float4 stream -> BCE + LDS nibbles --
    const int rlow = lane & 7;                       // row offset within octet
    const int quad = lane >> 3;                      // col quad within strip
    const size_t f4base = ((size_t)n * HH + (size_t)(wv * 128 + rlow)) * (WW / 4)
                        + (size_t)(strip * 8 + quad);
    const float4* Pp = (const float4*)pred + f4base;
    const float4* Tp = (const float4*)tgt  + f4base;

    // BCE (t in {0,1}): max(p,0)-p*t+log1p(e^-|p|) = ln2*log2(1+2^{(1-2t)p*log2e})
    // batch 8 px: one log2 of the product of eight (1+z) terms.
    float bsum = 0.f;                                // log2 units
    unsigned long long nv = 0ull;

    float4 pa = Pp[0],    ta = Tp[0];
    float4 pb = Pp[2048], tb = Tp[2048];

#pragma unroll 1
    for (int k = 0; k < 16; k += 2) {                // 2 row-steps per iter
        const unsigned kn0 = (k < 14) ? (unsigned)((k + 2) * 2048) : 0u;
        const unsigned kn1 = (k < 14) ? (unsigned)((k + 3) * 2048) : 0u;
        const float4 pc = Pp[kn0], tc = Tp[kn0];     // prefetch 2 steps ahead
        const float4 pd = Pp[kn1], td = Tp[kn1];

        const float a0 = EXP2F(fmaf(ta.x, -2.f * L2E, L2E) * pa.x);
        const float a1 = EXP2F(fmaf(ta.y, -2.f * L2E, L2E) * pa.y);
        const float a2 = EXP2F(fmaf(ta.z, -2.f * L2E, L2E) * pa.z);
        const float a3 = EXP2F(fmaf(ta.w, -2.f * L2E, L2E) * pa.w);
        const float wa0 = 1.f + a0;
        const float wa01 = fmaf(wa0, a1, wa0);
        const float wa2 = 1.f + a2;
        const float wa23 = fmaf(wa2, a3, wa2);

        const float b0 = EXP2F(fmaf(tb.x, -2.f * L2E, L2E) * pb.x);
        const float b1 = EXP2F(fmaf(tb.y, -2.f * L2E, L2E) * pb.y);
        const float b2 = EXP2F(fmaf(tb.z, -2.f * L2E, L2E) * pb.z);
        const float b3 = EXP2F(fmaf(tb.w, -2.f * L2E, L2E) * pb.w);
        const float wb0 = 1.f + b0;
        const float wb01 = fmaf(wb0, b1, wb0);
        const float wb2 = 1.f + b2;
        const float wb23 = fmaf(wb2, b3, wb2);

        bsum += LOG2F((wa01 * wa23) * (wb01 * wb23));   // 1 log per 8 px

        const unsigned tna = (unsigned)ta.x | ((unsigned)ta.y << 1) |
                             ((unsigned)ta.z << 2) | ((unsigned)ta.w << 3);
        const unsigned pna = (pa.x > 0.f ? 1u : 0u) | (pa.y > 0.f ? 2u : 0u) |
                             (pa.z > 0.f ? 4u : 0u) | (pa.w > 0.f ? 8u : 0u);
        const unsigned tnb = (unsigned)tb.x | ((unsigned)tb.y << 1) |
                             ((unsigned)tb.z << 2) | ((unsigned)tb.w << 3);
        const unsigned pnb = (pb.x > 0.f ? 1u : 0u) | (pb.y > 0.f ? 2u : 0u) |
                             (pb.z > 0.f ? 4u : 0u) | (pb.w > 0.f ? 8u : 0u);
        nv |= (unsigned long long)(tna | (pna << 4)) << (8 * (k & 7));
        nv |= (unsigned long long)(tnb | (pnb << 4)) << (8 * ((k + 1) & 7));
        if (((k + 1) & 7) == 7) {
            nibw[wv * 2 + (k >> 3)][quad * 8 + rlow] = nv;
            nv = 0ull;
        }
        pa = pc; ta = tc; pb = pd; tb = td;          // rotate pipeline
    }
    __syncthreads();

    // ---------------- Phase B: masks from LDS, popcount-dilation scan --------
    const int c   = tid & 31;                        // column within strip
    const int q   = tid >> 5;                        // 64-row chunk (0..15)
    const int h0  = q * 64;
    const int qs  = (c >> 2) * 8;
    const int tsh = c & 3;

    unsigned long long tw = 0ull, pw = 0ull;
#pragma unroll
    for (int r = 0; r < 8; ++r) {
        const unsigned long long x   = nibw[q][qs + r];
        const unsigned long long tb2 = (x >> tsh)       & 0x0101010101010101ULL;
        const unsigned long long pb2 = (x >> (4 + tsh)) & 0x0101010101010101ULL;
        tw |= tb2 << r;
        pw |= pb2 << r;
    }

    const int first = tw ? __builtin_ctzll(tw) : -1;
    const int last  = tw ? (63 - __builtin_clzll(tw)) : -1;
    st_first[q][c] = first;
    st_last[q][c]  = last;
    __syncthreads();

    // cross-chunk carries
    int U = BIGD;                                    // dist from row h0-1 up to nearest target
    for (int k = q - 1; k >= 0; --k) {
        const int l2 = st_last[k][c];
        if (l2 >= 0) { U = (h0 - 1) - (k * 64 + l2); break; }
    }
    int nxt_below = BIGD;                            // abs row of first target below chunk
    for (int k = q + 1; k < 16; ++k) {
        const int fs = st_first[k][c];
        if (fs >= 0) { nxt_below = k * 64 + fs; break; }
    }

    // count: d>0 exactly at non-target pred rows
    const unsigned cnt = (unsigned)__popcll(pw & ~tw);

    // tot = sum_{k=0}^{H-1} popc(pw & ~C_k), C_k = tw dilated k + boundary masks
    unsigned tot = 0u;
    {
        unsigned long long T = tw, ma = 0ull, mb = 0ull;
        const int nbm64 = nxt_below - h0 - 64;       // k threshold for mb top bit
        unsigned long long m = pw & ~T;
        for (int k = 0; (k < HH) && m; ++k) {
            tot += (unsigned)__popcll(m);            // pixels with d >= k+1
            T |= (T << 1) | (T >> 1);                // dilate to radius k+1
            ma = (ma << 1) | ((k >= U) ? 1ull : 0ull);
            mb = (mb >> 1) | ((k >= nbm64) ? 0x8000000000000000ull : 0ull);
            m &= ~(T | ma | mb);
        }
    }

    // ---------------- block reduction: wave shuffles + one LDS hop -----------
    float rv = bsum;
    unsigned vt = tot, vc = cnt;
#pragma unroll
    for (int o = 32; o > 0; o >>= 1) {
        rv += __shfl_down(rv, o);
        vt += __shfl_down(vt, o);
        vc += __shfl_down(vc, o);
    }
    if (lane == 0) { rfw[wv] = rv; rtw[wv] = vt; rcw[wv] = vc; }
    __syncthreads();

    // ---------------- publish partial + ticket; TRUE last block finalizes ----
    // ticket is memset to 0 on the stream before this kernel, so old==NBLK-1
    // identifies the final arriver (all other payloads already released).
    if (tid == 0) {
        float sf = 0.f; unsigned st = 0u, sc = 0u;
#pragma unroll
        for (int i = 0; i < 8; ++i) { sf += rfw[i]; st += rtw[i]; sc += rcw[i]; }
        bceP[bid] = (double)sf;                      // log2 units
        totP[bid] = st;
        cntP[bid] = sc;
        __threadfence();                             // release: writeback to coherent point
        const unsigned old = atomicAdd(ticket, 1u);  // device-scope RMW (m20)
        lastFlag = (old == NBLK - 1) ? 1 : 0;
    }
    __syncthreads();
    if (lastFlag == 0) return;

    __threadfence();                                 // acquire in EVERY reading thread (G16)

    // last block: reduce the 1024 slots (L2/MALL-hot) and write the scalar
    double             fr = bceP[tid] + bceP[tid + 512];
    unsigned long long ft = (unsigned long long)totP[tid]
                          + (unsigned long long)totP[tid + 512];
    unsigned           fc = cntP[tid] + cntP[tid + 512];
#pragma unroll
    for (int o = 32; o > 0; o >>= 1) {
        fr += __shfl_down(fr, o);
        ft += __shfl_down(ft, o);
        fc += __shfl_down(fc, o);
    }
    if (lane == 0) { fr8[wv] = fr; ft8[wv] = ft; fc8[wv] = fc; }
    __syncthreads();
    if (tid == 0) {
        double sf = 0.0; unsigned long long st = 0ull; unsigned sc = 0u;
#pragma unroll
        for (int i = 0; i < 8; ++i) { sf += fr8[i]; st += ft8[i]; sc += fc8[i]; }
        const double LN2 = 0.69314718055994530942;
        const double bce = LN2 * sf / (double)((size_t)NIMG * HH * WW);
        double border = 0.0;
        if (st != 0ull) {
            const unsigned cc = (sc > 1u) ? sc : 1u;
            border = sqrt((double)st / (double)cc);
        }
        out[0] = (float)(bce + border);
    }
}

extern "C" void kernel_launch(void* const* d_in, const int* in_sizes, int n_in,
                              void* d_out, int out_size, void* d_ws, size_t ws_size,
                              hipStream_t stream) {
    const float* pred = (const float*)d_in[0];
    const float* tgt  = (const float*)d_in[1];
    float* out = (float*)d_out;

    double*   bceP   = (double*)d_ws;
    unsigned* totP   = (unsigned*)((char*)d_ws + 8192);
    unsigned* cntP   = (unsigned*)((char*)d_ws + 12288);
    unsigned* ticket = (unsigned*)((char*)d_ws + 16384);

    hipMemsetAsync(ticket, 0, 4, stream);   // seed ticket: last arriver draws NBLK-1
    dtl_main<<<NBLK, NT, 0, stream>>>(pred, tgt, bceP, totP, cntP, ticket, out);
}

// Round 14
// 55.901 us; speedup vs baseline: 1.5158x; 1.5158x over previous
//
#include <hip/hip_runtime.h>
#include <math.h>

#define HH   1024
#define WW   1024
#define NIMG 32
#define NBLK (NIMG * (WW / 32))     // 1024 blocks: (image, 32-col strip)
#define NT   512
#define BIGD (1<<20)
#define L2E  1.44269504088896340736f

#if __has_builtin(__builtin_amdgcn_exp2f)
#define EXP2F(x) __builtin_amdgcn_exp2f(x)
#else
#define EXP2F(x) exp2f(x)
#endif
#if __has_builtin(__builtin_amdgcn_logf)
#define LOG2F(x) __builtin_amdgcn_logf(x)
#else
#define LOG2F(x) log2f(x)
#endif

// d_ws layout: double bceP[NBLK]; unsigned totP[NBLK]; unsigned cntP[NBLK]
// NOTE (R13 lesson): cross-block result publication via per-block
// __threadfence()+ticket costs ~30us on multi-XCD CDNA (every co-resident
// block's release fence = XCD-L2 writeback + serialized device-scope RMW).
// The kernel boundary before dtl_final is ONE global release — cheaper.

__global__ __launch_bounds__(NT, 8) void dtl_main(const float* __restrict__ pred,
                                                  const float* __restrict__ tgt,
                                                  double* __restrict__ bceP,
                                                  unsigned* __restrict__ totP,
                                                  unsigned* __restrict__ cntP) {
    // nibw[row>>6][ quad*8 + (row&7) ] : byte s = nibble-pair for row
    // (row>>6)*64 + s*8 + (row&7), cols quad*4..+3 (T bits0-3, P bits4-7)
    __shared__ unsigned long long nibw[16][64];      // 8 KiB
    __shared__ int st_first[16][32];
    __shared__ int st_last[16][32];
    __shared__ float    rfw[8];
    __shared__ unsigned rtw[8], rcw[8];

    const int tid   = threadIdx.x;
    const int lane  = tid & 63;
    const int wv    = tid >> 6;                      // 0..7
    const int n     = blockIdx.x >> 5;               // image
    const int strip = blockIdx.x & 31;               // col base = strip*32

    // ---------------- Phase A: pipelined float4 stream -> BCE + LDS nibbles --
    const int rlow = lane & 7;                       // row offset within octet
    const int quad = lane >> 3;                      // col quad within strip
    const size_t f4base = ((size_t)n * HH + (size_t)(wv * 128 + rlow)) * (WW / 4)
                        + (size_t)(strip * 8 + quad);
    const float4* Pp = (const float4*)pred + f4base;
    const float4* Tp = (const float4*)tgt  + f4base;

    // BCE (t in {0,1}): max(p,0)-p*t+log1p(e^-|p|) = ln2*log2(1+2^{(1-2t)p*log2e})
    // batch 8 px: one log2 of the product of eight (1+z) terms.
    float bsum = 0.f;                                // log2 units
    unsigned long long nv = 0ull;

    float4 pa = Pp[0],    ta = Tp[0];
    float4 pb = Pp[2048], tb = Tp[2048];

#pragma unroll 1
    for (int k = 0; k < 16; k += 2) {                // 2 row-steps per iter
        const unsigned kn0 = (k < 14) ? (unsigned)((k + 2) * 2048) : 0u;
        const unsigned kn1 = (k < 14) ? (unsigned)((k + 3) * 2048) : 0u;
        const float4 pc = Pp[kn0], tc = Tp[kn0];     // prefetch 2 steps ahead
        const float4 pd = Pp[kn1], td = Tp[kn1];

        const float a0 = EXP2F(fmaf(ta.x, -2.f * L2E, L2E) * pa.x);
        const float a1 = EXP2F(fmaf(ta.y, -2.f * L2E, L2E) * pa.y);
        const float a2 = EXP2F(fmaf(ta.z, -2.f * L2E, L2E) * pa.z);
        const float a3 = EXP2F(fmaf(ta.w, -2.f * L2E, L2E) * pa.w);
        const float wa0 = 1.f + a0;
        const float wa01 = fmaf(wa0, a1, wa0);
        const float wa2 = 1.f + a2;
        const float wa23 = fmaf(wa2, a3, wa2);

        const float b0 = EXP2F(fmaf(tb.x, -2.f * L2E, L2E) * pb.x);
        const float b1 = EXP2F(fmaf(tb.y, -2.f * L2E, L2E) * pb.y);
        const float b2 = EXP2F(fmaf(tb.z, -2.f * L2E, L2E) * pb.z);
        const float b3 = EXP2F(fmaf(tb.w, -2.f * L2E, L2E) * pb.w);
        const float wb0 = 1.f + b0;
        const float wb01 = fmaf(wb0, b1, wb0);
        const float wb2 = 1.f + b2;
        const float wb23 = fmaf(wb2, b3, wb2);

        bsum += LOG2F((wa01 * wa23) * (wb01 * wb23));   // 1 log per 8 px

        const unsigned tna = (unsigned)ta.x | ((unsigned)ta.y << 1) |
                             ((unsigned)ta.z << 2) | ((unsigned)ta.w << 3);
        const unsigned pna = (pa.x > 0.f ? 1u : 0u) | (pa.y > 0.f ? 2u : 0u) |
                             (pa.z > 0.f ? 4u : 0u) | (pa.w > 0.f ? 8u : 0u);
        const unsigned tnb = (unsigned)tb.x | ((unsigned)tb.y << 1) |
                             ((unsigned)tb.z << 2) | ((unsigned)tb.w << 3);
        const unsigned pnb = (pb.x > 0.f ? 1u : 0u) | (pb.y > 0.f ? 2u : 0u) |
                             (pb.z > 0.f ? 4u : 0u) | (pb.w > 0.f ? 8u : 0u);
        nv |= (unsigned long long)(tna | (pna << 4)) << (8 * (k & 7));
        nv |= (unsigned long long)(tnb | (pnb << 4)) << (8 * ((k + 1) & 7));
        if (((k + 1) & 7) == 7) {
            nibw[wv * 2 + (k >> 3)][quad * 8 + rlow] = nv;
            nv = 0ull;
        }
        pa = pc; ta = tc; pb = pd; tb = td;          // rotate pipeline
    }
    __syncthreads();

    // ---------------- Phase B: masks from LDS, popcount-dilation scan --------
    const int c   = tid & 31;                        // column within strip
    const int q   = tid >> 5;                        // 64-row chunk (0..15)
    const int h0  = q * 64;
    const int qs  = (c >> 2) * 8;
    const int tsh = c & 3;

    unsigned long long tw = 0ull, pw = 0ull;
#pragma unroll
    for (int r = 0; r < 8; ++r) {
        const unsigned long long x   = nibw[q][qs + r];
        const unsigned long long tb2 = (x >> tsh)       & 0x0101010101010101ULL;
        const unsigned long long pb2 = (x >> (4 + tsh)) & 0x0101010101010101ULL;
        tw |= tb2 << r;
        pw |= pb2 << r;
    }

    const int first = tw ? __builtin_ctzll(tw) : -1;
    const int last  = tw ? (63 - __builtin_clzll(tw)) : -1;
    st_first[q][c] = first;
    st_last[q][c]  = last;
    __syncthreads();

    // cross-chunk carries
    int U = BIGD;                                    // dist from row h0-1 up to nearest target
    for (int k = q - 1; k >= 0; --k) {
        const int l2 = st_last[k][c];
        if (l2 >= 0) { U = (h0 - 1) - (k * 64 + l2); break; }
    }
    int nxt_below = BIGD;                            // abs row of first target below chunk
    for (int k = q + 1; k < 16; ++k) {
        const int fs = st_first[k][c];
        if (fs >= 0) { nxt_below = k * 64 + fs; break; }
    }

    // count: d>0 exactly at non-target pred rows
    const unsigned cnt = (unsigned)__popcll(pw & ~tw);

    // tot = sum_{k=0}^{H-1} popc(pw & ~C_k), C_k = tw dilated k + boundary masks
    unsigned tot = 0u;
    {
        unsigned long long T = tw, ma = 0ull, mb = 0ull;
        const int nbm64 = nxt_below - h0 - 64;       // k threshold for mb top bit
        unsigned long long m = pw & ~T;
        for (int k = 0; (k < HH) && m; ++k) {
            tot += (unsigned)__popcll(m);            // pixels with d >= k+1
            T |= (T << 1) | (T >> 1);                // dilate to radius k+1
            ma = (ma << 1) | ((k >= U) ? 1ull : 0ull);
            mb = (mb >> 1) | ((k >= nbm64) ? 0x8000000000000000ull : 0ull);
            m &= ~(T | ma | mb);
        }
    }

    // ---------------- block reduction: wave shuffles + one LDS hop -----------
    float rv = bsum;
    unsigned vt = tot, vc = cnt;
#pragma unroll
    for (int o = 32; o > 0; o >>= 1) {
        rv += __shfl_down(rv, o);
        vt += __shfl_down(vt, o);
        vc += __shfl_down(vc, o);
    }
    if (lane == 0) { rfw[wv] = rv; rtw[wv] = vt; rcw[wv] = vc; }
    __syncthreads();
    if (tid == 0) {
        float sf = 0.f; unsigned st = 0u, sc = 0u;
#pragma unroll
        for (int i = 0; i < 8; ++i) { sf += rfw[i]; st += rtw[i]; sc += rcw[i]; }
        bceP[blockIdx.x] = (double)sf;               // log2 units
        totP[blockIdx.x] = st;
        cntP[blockIdx.x] = sc;
    }
}

// ---------------------------------------------------------------------------
// Final reduce: 1024 partial slots -> scalar loss. No atomics anywhere.
// ---------------------------------------------------------------------------
__global__ __launch_bounds__(512) void dtl_final(const double* __restrict__ bceP,
                                                 const unsigned* __restrict__ totP,
                                                 const unsigned* __restrict__ cntP,
                                                 float* __restrict__ out) {
    __shared__ double             rf[512];
    __shared__ unsigned long long rt[512];
    __shared__ unsigned           rc[512];
    const int t = threadIdx.x;
    rf[t] = bceP[t] + bceP[t + 512];
    rt[t] = (unsigned long long)totP[t] + (unsigned long long)totP[t + 512];
    rc[t] = cntP[t] + cntP[t + 512];
    __syncthreads();
    for (int off = 256; off > 0; off >>= 1) {
        if (t < off) { rf[t] += rf[t + off]; rt[t] += rt[t + off]; rc[t] += rc[t + off]; }
        __syncthreads();
    }
    if (t == 0) {
        const double LN2 = 0.69314718055994530942;
        const double bce = LN2 * rf[0] / (double)((size_t)NIMG * HH * WW);
        double border = 0.0;
        if (rt[0] != 0ull) {
            const unsigned cc = (rc[0] > 1u) ? rc[0] : 1u;
            border = sqrt((double)rt[0] / (double)cc);
        }
        out[0] = (float)(bce + border);
    }
}

extern "C" void kernel_launch(void* const* d_in, const int* in_sizes, int n_in,
                              void* d_out, int out_size, void* d_ws, size_t ws_size,
                              hipStream_t stream) {
    const float* pred = (const float*)d_in[0];
    const float* tgt  = (const float*)d_in[1];
    float* out = (float*)d_out;

    double*   bceP = (double*)d_ws;
    unsigned* totP = (unsigned*)((char*)d_ws + 8192);
    unsigned* cntP = totP + NBLK;

    dtl_main<<<NBLK, NT, 0, stream>>>(pred, tgt, bceP, totP, cntP);
    dtl_final<<<1, 512, 0, stream>>>(bceP, totP, cntP, out);
}